// Round 1
// baseline (1128.461 us; speedup 1.0000x reference)
//
#include <hip/hip_runtime.h>
#include <cstdint>
#include <cstddef>

#define DECAY 0.8f
#define OMD 0.2f            // 1 - decay
#define EPS_LAP 1e-5f
#define EPS_NORM 1e-6f

constexpr int ROWS  = 8192;   // b*n = 4*2048
constexpr int DIM   = 512;
constexpr int CODES = 8192;

// flat output offsets (floats), in reference return order
constexpr size_t OFF_Q    = 0;                      // quantize (4,2048,512)
constexpr size_t OFF_IND  = OFF_Q    + (size_t)ROWS * DIM;       // ind (4,2048)
constexpr size_t OFF_DIST = OFF_IND  + (size_t)ROWS;             // dist (4,2048,8192)
constexpr size_t OFF_NCS  = OFF_DIST + (size_t)ROWS * CODES;     // new_cluster_size (1,8192)
constexpr size_t OFF_NEA  = OFF_NCS  + (size_t)CODES;            // new_embed_avg (1,8192,512)
constexpr size_t OFF_NE   = OFF_NEA  + (size_t)CODES * DIM;      // new_embed (1,8192,512)

// ---------- helpers ----------

__device__ inline unsigned int ford(float f) {
    unsigned int u = __float_as_uint(f);
    return (u & 0x80000000u) ? ~u : (u | 0x80000000u);
}

// 256-thread block sum reduction; sm must be float[4]; all threads get result
__device__ inline float block_reduce_sum_256(float v, float* sm) {
    #pragma unroll
    for (int off = 32; off > 0; off >>= 1) v += __shfl_down(v, off, 64);
    __syncthreads();                    // protect sm reuse across calls
    if ((threadIdx.x & 63) == 0) sm[threadIdx.x >> 6] = v;
    __syncthreads();
    return sm[0] + sm[1] + sm[2] + sm[3];
}

// ---------- kernel 1: row l2-normalize x -> xn, and zero-init packed ----------

__global__ __launch_bounds__(256) void l2norm_rows(
    const float* __restrict__ x, float* __restrict__ xn,
    unsigned long long* __restrict__ packed) {
    __shared__ float sm[4];
    const int row = blockIdx.x;
    const int t = threadIdx.x;
    const float2 v = ((const float2*)(x + (size_t)row * DIM))[t];
    float ss = v.x * v.x + v.y * v.y;
    float total = block_reduce_sum_256(ss, sm);
    float norm = fmaxf(sqrtf(total), EPS_NORM);
    float2 o;
    o.x = v.x / norm;
    o.y = v.y / norm;
    ((float2*)(xn + (size_t)row * DIM))[t] = o;
    if (t == 0) packed[row] = 0ull;
}

// ---------- kernel 2: EMA init: ncs = decay*cs, nea = decay*ea ----------

__global__ __launch_bounds__(256) void ema_init(
    const float* __restrict__ cs, const float* __restrict__ ea,
    float* __restrict__ ncs, float* __restrict__ nea) {
    const int gid = blockIdx.x * 256 + threadIdx.x;   // 0 .. 1048575 (float4s of nea)
    float4 e = ((const float4*)ea)[gid];
    e.x *= DECAY; e.y *= DECAY; e.z *= DECAY; e.w *= DECAY;
    ((float4*)nea)[gid] = e;
    if (gid < CODES / 4) {
        float4 c = ((const float4*)cs)[gid];
        c.x *= DECAY; c.y *= DECAY; c.z *= DECAY; c.w *= DECAY;
        ((float4*)ncs)[gid] = c;
    }
}

// ---------- kernel 3: fp32 NT GEMM dist = xn @ embed^T, fused row-argmax ----------
// BM=BN=128, BK=16, 256 threads, 8x8 micro-tile per thread.

constexpr int BM = 128, BN = 128, BK = 16;

__global__ __launch_bounds__(256) void gemm_nt_argmax(
    const float* __restrict__ A,   // xn   [ROWS, DIM]
    const float* __restrict__ B,   // embed[CODES, DIM]
    float* __restrict__ D,         // dist [ROWS, CODES]
    unsigned long long* __restrict__ packed) {
    __shared__ float As[BK][BM + 4];
    __shared__ float Bs[BK][BN + 4];

    const int bm = blockIdx.y, bn = blockIdx.x;
    const int t = threadIdx.x;
    const int tx = t & 15, ty = t >> 4;

    float acc[8][8];
    #pragma unroll
    for (int i = 0; i < 8; i++)
        #pragma unroll
        for (int j = 0; j < 8; j++) acc[i][j] = 0.0f;

    // loader mapping: 512 float4 slots per tile, 2 per thread (s = t, t+256)
    const int r0 = t >> 2,          s0 = t & 3;
    const int r1 = (t + 256) >> 2,  s1 = (t + 256) & 3;
    const float4* a0p = (const float4*)(A + ((size_t)(bm * BM + r0)) * DIM) + s0;
    const float4* a1p = (const float4*)(A + ((size_t)(bm * BM + r1)) * DIM) + s1;
    const float4* b0p = (const float4*)(B + ((size_t)(bn * BN + r0)) * DIM) + s0;
    const float4* b1p = (const float4*)(B + ((size_t)(bn * BN + r1)) * DIM) + s1;

    for (int k0 = 0; k0 < DIM; k0 += BK) {
        const int k4 = k0 >> 2;   // offset in float4 units
        float4 av0 = a0p[k4], av1 = a1p[k4];
        float4 bv0 = b0p[k4], bv1 = b1p[k4];
        __syncthreads();          // previous iter's reads done before overwrite
        As[s0 * 4 + 0][r0] = av0.x; As[s0 * 4 + 1][r0] = av0.y;
        As[s0 * 4 + 2][r0] = av0.z; As[s0 * 4 + 3][r0] = av0.w;
        As[s1 * 4 + 0][r1] = av1.x; As[s1 * 4 + 1][r1] = av1.y;
        As[s1 * 4 + 2][r1] = av1.z; As[s1 * 4 + 3][r1] = av1.w;
        Bs[s0 * 4 + 0][r0] = bv0.x; Bs[s0 * 4 + 1][r0] = bv0.y;
        Bs[s0 * 4 + 2][r0] = bv0.z; Bs[s0 * 4 + 3][r0] = bv0.w;
        Bs[s1 * 4 + 0][r1] = bv1.x; Bs[s1 * 4 + 1][r1] = bv1.y;
        Bs[s1 * 4 + 2][r1] = bv1.z; Bs[s1 * 4 + 3][r1] = bv1.w;
        __syncthreads();

        #pragma unroll
        for (int k = 0; k < BK; k++) {
            float4 a_0 = *(const float4*)&As[k][ty * 8];
            float4 a_1 = *(const float4*)&As[k][ty * 8 + 4];
            float4 b_0 = *(const float4*)&Bs[k][tx * 8];
            float4 b_1 = *(const float4*)&Bs[k][tx * 8 + 4];
            float ar[8] = {a_0.x, a_0.y, a_0.z, a_0.w, a_1.x, a_1.y, a_1.z, a_1.w};
            float br[8] = {b_0.x, b_0.y, b_0.z, b_0.w, b_1.x, b_1.y, b_1.z, b_1.w};
            #pragma unroll
            for (int i = 0; i < 8; i++)
                #pragma unroll
                for (int j = 0; j < 8; j++)
                    acc[i][j] = fmaf(ar[i], br[j], acc[i][j]);
        }
    }

    // epilogue: store dist + fused per-row argmax
    const int col0 = bn * BN + tx * 8;
    #pragma unroll
    for (int i = 0; i < 8; i++) {
        const int row = bm * BM + ty * 8 + i;
        float4 c0 = make_float4(acc[i][0], acc[i][1], acc[i][2], acc[i][3]);
        float4 c1 = make_float4(acc[i][4], acc[i][5], acc[i][6], acc[i][7]);
        float4* dp = (float4*)(D + (size_t)row * CODES + col0);
        dp[0] = c0; dp[1] = c1;

        float bv = acc[i][0]; int bj = 0;
        #pragma unroll
        for (int j = 1; j < 8; j++)
            if (acc[i][j] > bv) { bv = acc[i][j]; bj = j; }
        unsigned long long key =
            ((unsigned long long)ford(bv) << 32) |
            (unsigned long long)(unsigned int)(CODES - 1 - (col0 + bj));
        // max across the 16 lanes sharing this row (same ty, tx=0..15)
        #pragma unroll
        for (int m = 1; m < 16; m <<= 1) {
            unsigned long long o = __shfl_xor(key, m, 64);
            if (o > key) key = o;
        }
        if (tx == 0) atomicMax(&packed[row], key);
    }
}

// ---------- kernel 4: per-row finalize: ind, quantize gather, bins + embed_sum ----------

__global__ __launch_bounds__(128) void finalize_rows(
    const unsigned long long* __restrict__ packed,
    const float* __restrict__ embed, const float* __restrict__ xn,
    float* __restrict__ q, float* __restrict__ indf,
    float* __restrict__ ncs, float* __restrict__ nea) {
    const int n = blockIdx.x;
    __shared__ int sc;
    if (threadIdx.x == 0) {
        unsigned long long key = packed[n];
        int c = CODES - 1 - (int)(key & 0xFFFFFFFFull);
        sc = c;
        indf[n] = (float)c;
        atomicAdd(&ncs[c], OMD);
    }
    __syncthreads();
    const int c = sc;
    const int d0 = threadIdx.x * 4;
    float4 xv = *(const float4*)(xn + (size_t)n * DIM + d0);      // read BEFORE q write (aliasing fallback)
    float4 ev = *(const float4*)(embed + (size_t)c * DIM + d0);
    *(float4*)(q + (size_t)n * DIM + d0) = ev;
    float* dst = nea + (size_t)c * DIM + d0;
    atomicAdd(dst + 0, OMD * xv.x);
    atomicAdd(dst + 1, OMD * xv.y);
    atomicAdd(dst + 2, OMD * xv.z);
    atomicAdd(dst + 3, OMD * xv.w);
}

// ---------- kernel 5: new_embed = l2norm(new_embed_avg / smoothed) ----------

__global__ __launch_bounds__(256) void embed_norm(
    const float* __restrict__ ncs, const float* __restrict__ nea,
    float* __restrict__ ne) {
    __shared__ float sm[4];
    const int c = blockIdx.x;
    const int t = threadIdx.x;
    // denom = sum(new_cluster_size): 8192 floats, L1/L2-hot across blocks
    float local = 0.0f;
    for (int i = t; i < CODES; i += 256) local += ncs[i];
    const float denom = block_reduce_sum_256(local, sm);
    const float s = (ncs[c] + EPS_LAP) / (denom + (float)CODES * EPS_LAP) * denom;
    float2 v = ((const float2*)(nea + (size_t)c * DIM))[t];
    float2 w;
    w.x = v.x / s;
    w.y = v.y / s;
    const float total = block_reduce_sum_256(w.x * w.x + w.y * w.y, sm);
    const float norm = fmaxf(sqrtf(total), EPS_NORM);
    float2 o;
    o.x = w.x / norm;
    o.y = w.y / norm;
    ((float2*)(ne + (size_t)c * DIM))[t] = o;
}

// ---------- host ----------

extern "C" void kernel_launch(void* const* d_in, const int* in_sizes, int n_in,
                              void* d_out, int out_size, void* d_ws, size_t ws_size,
                              hipStream_t stream) {
    const float* x     = (const float*)d_in[0];
    const float* embed = (const float*)d_in[1];
    const float* cs    = (const float*)d_in[2];
    const float* ea    = (const float*)d_in[3];

    float* out  = (float*)d_out;
    float* q    = out + OFF_Q;
    float* indf = out + OFF_IND;
    float* dist = out + OFF_DIST;
    float* ncs  = out + OFF_NCS;
    float* nea  = out + OFF_NEA;
    float* ne   = out + OFF_NE;

    const size_t xn_bytes = (size_t)ROWS * DIM * sizeof(float);
    const size_t packed_bytes = (size_t)ROWS * sizeof(unsigned long long);

    float* xn;
    unsigned long long* packed;
    if (ws_size >= xn_bytes + packed_bytes) {
        xn = (float*)d_ws;
        packed = (unsigned long long*)((char*)d_ws + xn_bytes);
    } else {
        // fallback: xn lives in quantize region (finalize reads xn[n] before writing q[n]);
        // packed lives at start of new_embed region (consumed before embed_norm writes it)
        xn = q;
        packed = (unsigned long long*)ne;
    }

    hipLaunchKernelGGL(l2norm_rows, dim3(ROWS), dim3(256), 0, stream, x, xn, packed);
    hipLaunchKernelGGL(ema_init, dim3((ROWS * DIM / 4) / 256), dim3(256), 0, stream, cs, ea, ncs, nea);
    hipLaunchKernelGGL(gemm_nt_argmax, dim3(CODES / BN, ROWS / BM), dim3(256), 0, stream,
                       xn, embed, dist, packed);
    hipLaunchKernelGGL(finalize_rows, dim3(ROWS), dim3(128), 0, stream,
                       packed, embed, xn, q, indf, ncs, nea);
    hipLaunchKernelGGL(embed_norm, dim3(CODES), dim3(256), 0, stream, ncs, nea, ne);
}

// Round 2
// 686.242 us; speedup vs baseline: 1.6444x; 1.6444x over previous
//
#include <hip/hip_runtime.h>
#include <cstdint>
#include <cstddef>

#define DECAY 0.8f
#define OMD 0.2f            // 1 - decay
#define EPS_LAP 1e-5f
#define EPS_NORM 1e-6f
#define DELTA 5e-4f         // refinement margin (>> 12x worst-case bf16x3 error)

constexpr int ROWS  = 8192;   // b*n = 4*2048
constexpr int DIM   = 512;
constexpr int CODES = 8192;

// flat output offsets (floats), in reference return order
constexpr size_t OFF_Q    = 0;
constexpr size_t OFF_IND  = OFF_Q    + (size_t)ROWS * DIM;
constexpr size_t OFF_DIST = OFF_IND  + (size_t)ROWS;
constexpr size_t OFF_NCS  = OFF_DIST + (size_t)ROWS * CODES;
constexpr size_t OFF_NEA  = OFF_NCS  + (size_t)CODES;
constexpr size_t OFF_NE   = OFF_NEA  + (size_t)CODES * DIM;

typedef __bf16 bf16x8_t __attribute__((ext_vector_type(8)));
typedef float  f32x16_t __attribute__((ext_vector_type(16)));

// ---------- helpers ----------

__device__ inline unsigned int ford(float f) {
    unsigned int u = __float_as_uint(f);
    return (u & 0x80000000u) ? ~u : (u | 0x80000000u);
}
__device__ inline float unford(unsigned int u) {
    unsigned int v = (u & 0x80000000u) ? (u & 0x7fffffffu) : ~u;
    return __uint_as_float(v);
}

__device__ inline float block_reduce_sum_256(float v, float* sm) {
    #pragma unroll
    for (int off = 32; off > 0; off >>= 1) v += __shfl_down(v, off, 64);
    __syncthreads();
    if ((threadIdx.x & 63) == 0) sm[threadIdx.x >> 6] = v;
    __syncthreads();
    return sm[0] + sm[1] + sm[2] + sm[3];
}

__device__ inline void split_bf16(float v, unsigned short& h, unsigned short& l) {
    __bf16 hb = (__bf16)v;
    float hf = (float)hb;
    __bf16 lb = (__bf16)(v - hf);
    h = *(unsigned short*)&hb;
    l = *(unsigned short*)&lb;
}

// ---------- kernel 1: decompose x (l2norm) and embed into bf16 hi/lo; zero packed ----------

__global__ __launch_bounds__(256) void decompose(
    const float* __restrict__ x, const float* __restrict__ embed,
    unsigned short* __restrict__ Ah, unsigned short* __restrict__ Al,
    unsigned short* __restrict__ Bh, unsigned short* __restrict__ Bl,
    unsigned long long* __restrict__ packed) {
    __shared__ float sm[4];
    const int t = threadIdx.x;
    if ((int)blockIdx.x < ROWS) {
        const int row = blockIdx.x;
        const float2 v = ((const float2*)(x + (size_t)row * DIM))[t];
        const float total = block_reduce_sum_256(v.x * v.x + v.y * v.y, sm);
        const float nx = fmaxf(sqrtf(total), EPS_NORM);
        const float a0 = v.x / nx, a1 = v.y / nx;
        unsigned short h0, l0, h1, l1;
        split_bf16(a0, h0, l0); split_bf16(a1, h1, l1);
        ushort2 hh; hh.x = h0; hh.y = h1;
        ushort2 ll; ll.x = l0; ll.y = l1;
        ((ushort2*)(Ah + (size_t)row * DIM))[t] = hh;
        ((ushort2*)(Al + (size_t)row * DIM))[t] = ll;
    } else {
        const int row = blockIdx.x - ROWS;
        const float2 v = ((const float2*)(embed + (size_t)row * DIM))[t];
        unsigned short h0, l0, h1, l1;
        split_bf16(v.x, h0, l0); split_bf16(v.y, h1, l1);
        ushort2 hh; hh.x = h0; hh.y = h1;
        ushort2 ll; ll.x = l0; ll.y = l1;
        ((ushort2*)(Bh + (size_t)row * DIM))[t] = hh;
        ((ushort2*)(Bl + (size_t)row * DIM))[t] = ll;
        if (t == 0) packed[row] = 0ull;
    }
}

// ---------- kernel 2: bf16x3 MFMA GEMM dist = xn @ embed^T + fused argmax ----------
// 128x128 block tile, 4 waves of 64x64, 32x32x16 bf16 MFMA, BK=32.

constexpr int LDK = 40;   // padded shorts per LDS row (32 + 8) -> conflict-free b128 frag reads

__global__ __launch_bounds__(256) void gemm_bf16x3(
    const unsigned short* __restrict__ Ah, const unsigned short* __restrict__ Al,
    const unsigned short* __restrict__ Bh, const unsigned short* __restrict__ Bl,
    float* __restrict__ D,
    unsigned long long* __restrict__ packed,
    unsigned long long* __restrict__ blockkey) {
    __shared__ __align__(16) unsigned short Ah_s[128 * LDK];
    __shared__ __align__(16) unsigned short Al_s[128 * LDK];
    __shared__ __align__(16) unsigned short Bh_s[128 * LDK];
    __shared__ __align__(16) unsigned short Bl_s[128 * LDK];
    __shared__ unsigned long long rowkey[128];

    const int t = threadIdx.x;
    const int bn = blockIdx.x, bm = blockIdx.y;
    const int lane = t & 63, w = t >> 6;
    const int wm = w >> 1, wn = w & 1;
    const int lr = lane & 31, kg = lane >> 5;

    if (t < 128) rowkey[t] = 0ull;

    // loader: thread t stages 16B chunks (row m = id>>2, chunk c = id&3) for ids t and t+256
    const int lm0 = t >> 2, lc0 = t & 3;
    const size_t offA = (size_t)(bm * 128 + lm0) * DIM + lc0 * 8;
    const size_t offB = (size_t)(bn * 128 + lm0) * DIM + lc0 * 8;
    const int d0 = lm0 * LDK + lc0 * 8, d1 = d0 + 64 * LDK;

    f32x16_t acc00, acc01, acc10, acc11;
    #pragma unroll
    for (int i = 0; i < 16; i++) { acc00[i] = 0.f; acc01[i] = 0.f; acc10[i] = 0.f; acc11[i] = 0.f; }

    float4 r0 = *(const float4*)(Ah + offA);
    float4 r1 = *(const float4*)(Ah + offA + 64 * DIM);
    float4 r2 = *(const float4*)(Al + offA);
    float4 r3 = *(const float4*)(Al + offA + 64 * DIM);
    float4 r4 = *(const float4*)(Bh + offB);
    float4 r5 = *(const float4*)(Bh + offB + 64 * DIM);
    float4 r6 = *(const float4*)(Bl + offB);
    float4 r7 = *(const float4*)(Bl + offB + 64 * DIM);

    const int fa = (wm * 64 + lr) * LDK + kg * 8;
    const int fb = (wn * 64 + lr) * LDK + kg * 8;

    for (int k0 = 0; k0 < DIM; k0 += 32) {
        __syncthreads();
        *(float4*)&Ah_s[d0] = r0; *(float4*)&Ah_s[d1] = r1;
        *(float4*)&Al_s[d0] = r2; *(float4*)&Al_s[d1] = r3;
        *(float4*)&Bh_s[d0] = r4; *(float4*)&Bh_s[d1] = r5;
        *(float4*)&Bl_s[d0] = r6; *(float4*)&Bl_s[d1] = r7;
        __syncthreads();
        if (k0 + 32 < DIM) {
            const size_t oA = offA + (k0 + 32), oB = offB + (k0 + 32);
            r0 = *(const float4*)(Ah + oA); r1 = *(const float4*)(Ah + oA + 64 * DIM);
            r2 = *(const float4*)(Al + oA); r3 = *(const float4*)(Al + oA + 64 * DIM);
            r4 = *(const float4*)(Bh + oB); r5 = *(const float4*)(Bh + oB + 64 * DIM);
            r6 = *(const float4*)(Bl + oB); r7 = *(const float4*)(Bl + oB + 64 * DIM);
        }
        #pragma unroll
        for (int s = 0; s < 2; s++) {
            const int so = s * 16;
            bf16x8_t a_h0 = *(const bf16x8_t*)&Ah_s[fa + so];
            bf16x8_t a_h1 = *(const bf16x8_t*)&Ah_s[fa + 32 * LDK + so];
            bf16x8_t a_l0 = *(const bf16x8_t*)&Al_s[fa + so];
            bf16x8_t a_l1 = *(const bf16x8_t*)&Al_s[fa + 32 * LDK + so];
            bf16x8_t b_h0 = *(const bf16x8_t*)&Bh_s[fb + so];
            bf16x8_t b_h1 = *(const bf16x8_t*)&Bh_s[fb + 32 * LDK + so];
            bf16x8_t b_l0 = *(const bf16x8_t*)&Bl_s[fb + so];
            bf16x8_t b_l1 = *(const bf16x8_t*)&Bl_s[fb + 32 * LDK + so];
            acc00 = __builtin_amdgcn_mfma_f32_32x32x16_bf16(a_h0, b_h0, acc00, 0, 0, 0);
            acc01 = __builtin_amdgcn_mfma_f32_32x32x16_bf16(a_h0, b_h1, acc01, 0, 0, 0);
            acc10 = __builtin_amdgcn_mfma_f32_32x32x16_bf16(a_h1, b_h0, acc10, 0, 0, 0);
            acc11 = __builtin_amdgcn_mfma_f32_32x32x16_bf16(a_h1, b_h1, acc11, 0, 0, 0);
            acc00 = __builtin_amdgcn_mfma_f32_32x32x16_bf16(a_h0, b_l0, acc00, 0, 0, 0);
            acc01 = __builtin_amdgcn_mfma_f32_32x32x16_bf16(a_h0, b_l1, acc01, 0, 0, 0);
            acc10 = __builtin_amdgcn_mfma_f32_32x32x16_bf16(a_h1, b_l0, acc10, 0, 0, 0);
            acc11 = __builtin_amdgcn_mfma_f32_32x32x16_bf16(a_h1, b_l1, acc11, 0, 0, 0);
            acc00 = __builtin_amdgcn_mfma_f32_32x32x16_bf16(a_l0, b_h0, acc00, 0, 0, 0);
            acc01 = __builtin_amdgcn_mfma_f32_32x32x16_bf16(a_l0, b_h1, acc01, 0, 0, 0);
            acc10 = __builtin_amdgcn_mfma_f32_32x32x16_bf16(a_l1, b_h0, acc10, 0, 0, 0);
            acc11 = __builtin_amdgcn_mfma_f32_32x32x16_bf16(a_l1, b_h1, acc11, 0, 0, 0);
        }
    }

    // epilogue: store dist + per-row argmax (C/D: col=lane&31, row=(reg&3)+8*(reg>>2)+4*(lane>>5))
    const int colb = bn * 128 + wn * 64;
    const int rowb = bm * 128;
    #pragma unroll
    for (int mt = 0; mt < 2; mt++) {
        const f32x16_t a0 = mt ? acc10 : acc00;
        const f32x16_t a1 = mt ? acc11 : acc01;
        #pragma unroll
        for (int reg = 0; reg < 16; reg++) {
            const int rloc = wm * 64 + mt * 32 + (reg & 3) + 8 * (reg >> 2) + 4 * kg;
            const size_t rb = (size_t)(rowb + rloc) * CODES;
            const float v0 = a0[reg], v1 = a1[reg];
            D[rb + colb + lr] = v0;
            D[rb + colb + 32 + lr] = v1;
            unsigned long long key0 =
                ((unsigned long long)ford(v0) << 32) | (unsigned)(CODES - 1 - (colb + lr));
            unsigned long long key1 =
                ((unsigned long long)ford(v1) << 32) | (unsigned)(CODES - 1 - (colb + 32 + lr));
            unsigned long long key = key0 > key1 ? key0 : key1;
            #pragma unroll
            for (int m = 1; m <= 16; m <<= 1) {
                unsigned long long o = __shfl_xor(key, m, 64);
                if (o > key) key = o;
            }
            if (lr == 0) atomicMax(&rowkey[rloc], key);
        }
    }
    __syncthreads();
    if (t < 128) {
        const unsigned long long key = rowkey[t];
        const int grow = rowb + t;
        atomicMax(&packed[grow], key);
        blockkey[(size_t)grow * 64 + bn] = key;
    }
}

// ---------- kernel 3: refine argmax exactly (sequential fp32, same order as a plain k-loop) ----------

__global__ __launch_bounds__(64) void refine(
    const unsigned long long* __restrict__ packed,
    const unsigned long long* __restrict__ blockkey,
    const float* __restrict__ D,
    const float* __restrict__ x,
    const float* __restrict__ embed,
    float* __restrict__ indf) {
    const int row = blockIdx.x, t = threadIdx.x;
    __shared__ int cnt;
    __shared__ int cand[32];
    __shared__ float cx[DIM];
    if (t == 0) cnt = 0;
    const unsigned long long pk = packed[row];
    const float m = unford((unsigned int)(pk >> 32));
    const float thr = m - DELTA;
    const unsigned long long bk = blockkey[(size_t)row * 64 + t];
    const float bv = unford((unsigned int)(bk >> 32));
    unsigned long long bmask = __ballot(bv >= thr);
    __syncthreads();
    while (bmask) {
        const int b = __ffsll((unsigned long long)bmask) - 1;
        bmask &= bmask - 1;
        #pragma unroll
        for (int i = 0; i < 2; i++) {
            const int col = b * 128 + i * 64 + t;
            const float v = D[(size_t)row * CODES + col];
            if (v >= thr) {
                const int p = atomicAdd(&cnt, 1);
                if (p < 32) cand[p] = col;
            }
        }
    }
    __syncthreads();
    const int n = cnt;
    int best;
    if (n <= 1) {
        best = CODES - 1 - (int)(pk & 0xffffffffull);
    } else {
        float ss = 0.f;
        for (int k = t; k < DIM; k += 64) { const float xv = x[(size_t)row * DIM + k]; ss += xv * xv; }
        #pragma unroll
        for (int o = 32; o > 0; o >>= 1) ss += __shfl_xor(ss, o, 64);
        const float nx = fmaxf(sqrtf(ss), EPS_NORM);
        for (int k = t; k < DIM; k += 64) cx[k] = x[(size_t)row * DIM + k] / nx;
        __syncthreads();
        unsigned long long bkey = 0ull;
        if (t < n && t < 32) {
            const int c = cand[t];
            const float* e = embed + (size_t)c * DIM;
            float acc = 0.f;
            for (int k = 0; k < DIM; k++) acc = fmaf(cx[k], e[k], acc);
            bkey = ((unsigned long long)ford(acc) << 32) | (unsigned)(CODES - 1 - c);
        }
        #pragma unroll
        for (int mm = 1; mm <= 32; mm <<= 1) {
            unsigned long long o = __shfl_xor(bkey, mm, 64);
            if (o > bkey) bkey = o;
        }
        best = CODES - 1 - (int)(bkey & 0xffffffffull);
    }
    if (t == 0) indf[row] = (float)best;
}

// ---------- kernel 4: EMA init: ncs = decay*cs, nea = decay*ea ----------

__global__ __launch_bounds__(256) void ema_init(
    const float* __restrict__ cs, const float* __restrict__ ea,
    float* __restrict__ ncs, float* __restrict__ nea) {
    const int gid = blockIdx.x * 256 + threadIdx.x;
    float4 e = ((const float4*)ea)[gid];
    e.x *= DECAY; e.y *= DECAY; e.z *= DECAY; e.w *= DECAY;
    ((float4*)nea)[gid] = e;
    if (gid < CODES / 4) {
        float4 c = ((const float4*)cs)[gid];
        c.x *= DECAY; c.y *= DECAY; c.z *= DECAY; c.w *= DECAY;
        ((float4*)ncs)[gid] = c;
    }
}

// ---------- kernel 5: per-row finalize: quantize gather, bins + embed_sum ----------

__global__ __launch_bounds__(128) void finalize_rows(
    const float* __restrict__ indf, const float* __restrict__ x,
    const float* __restrict__ embed,
    float* __restrict__ q, float* __restrict__ ncs, float* __restrict__ nea) {
    __shared__ float sm[2];
    const int nrow = blockIdx.x, t = threadIdx.x;
    const int c = (int)indf[nrow];
    const int d0 = t * 4;
    const float4 xv = *(const float4*)(x + (size_t)nrow * DIM + d0);
    float ss = xv.x * xv.x + xv.y * xv.y + xv.z * xv.z + xv.w * xv.w;
    #pragma unroll
    for (int o = 32; o > 0; o >>= 1) ss += __shfl_down(ss, o, 64);
    if ((t & 63) == 0) sm[t >> 6] = ss;
    __syncthreads();
    const float nx = fmaxf(sqrtf(sm[0] + sm[1]), EPS_NORM);
    const float4 ev = *(const float4*)(embed + (size_t)c * DIM + d0);
    *(float4*)(q + (size_t)nrow * DIM + d0) = ev;
    float* dst = nea + (size_t)c * DIM + d0;
    atomicAdd(dst + 0, OMD * (xv.x / nx));
    atomicAdd(dst + 1, OMD * (xv.y / nx));
    atomicAdd(dst + 2, OMD * (xv.z / nx));
    atomicAdd(dst + 3, OMD * (xv.w / nx));
    if (t == 0) atomicAdd(&ncs[c], OMD);
}

// ---------- kernel 6: new_embed = l2norm(new_embed_avg / smoothed) ----------

__global__ __launch_bounds__(256) void embed_norm(
    const float* __restrict__ ncs, const float* __restrict__ nea,
    float* __restrict__ ne) {
    __shared__ float sm[4];
    const int c = blockIdx.x;
    const int t = threadIdx.x;
    float local = 0.0f;
    for (int i = t; i < CODES; i += 256) local += ncs[i];
    const float denom = block_reduce_sum_256(local, sm);
    const float s = (ncs[c] + EPS_LAP) / (denom + (float)CODES * EPS_LAP) * denom;
    const float2 v = ((const float2*)(nea + (size_t)c * DIM))[t];
    float2 wv;
    wv.x = v.x / s;
    wv.y = v.y / s;
    const float total = block_reduce_sum_256(wv.x * wv.x + wv.y * wv.y, sm);
    const float norm = fmaxf(sqrtf(total), EPS_NORM);
    float2 o;
    o.x = wv.x / norm;
    o.y = wv.y / norm;
    ((float2*)(ne + (size_t)c * DIM))[t] = o;
}

// ---------- host ----------

extern "C" void kernel_launch(void* const* d_in, const int* in_sizes, int n_in,
                              void* d_out, int out_size, void* d_ws, size_t ws_size,
                              hipStream_t stream) {
    const float* x     = (const float*)d_in[0];
    const float* embed = (const float*)d_in[1];
    const float* cs    = (const float*)d_in[2];
    const float* ea    = (const float*)d_in[3];

    float* out  = (float*)d_out;
    float* q    = out + OFF_Q;
    float* indf = out + OFF_IND;
    float* dist = out + OFF_DIST;
    float* ncs  = out + OFF_NCS;
    float* nea  = out + OFF_NEA;
    float* ne   = out + OFF_NE;

    // scratch aliased into later-written output regions (no ws_size dependency):
    // ah/al in new_embed (written last), bh/bl in quantize (written by finalize),
    // packed+blockkey in new_embed_avg (written by ema_init, which runs after refine).
    unsigned short* Ah = (unsigned short*)ne;
    unsigned short* Al = Ah + (size_t)ROWS * DIM;
    unsigned short* Bh = (unsigned short*)q;
    unsigned short* Bl = Bh + (size_t)CODES * DIM;
    unsigned long long* packed   = (unsigned long long*)nea;
    unsigned long long* blockkey = packed + ROWS;

    hipLaunchKernelGGL(decompose, dim3(ROWS + CODES), dim3(256), 0, stream,
                       x, embed, Ah, Al, Bh, Bl, packed);
    hipLaunchKernelGGL(gemm_bf16x3, dim3(CODES / 128, ROWS / 128), dim3(256), 0, stream,
                       Ah, Al, Bh, Bl, dist, packed, blockkey);
    hipLaunchKernelGGL(refine, dim3(ROWS), dim3(64), 0, stream,
                       packed, blockkey, dist, x, embed, indf);
    hipLaunchKernelGGL(ema_init, dim3((CODES * DIM / 4) / 256), dim3(256), 0, stream,
                       cs, ea, ncs, nea);
    hipLaunchKernelGGL(finalize_rows, dim3(ROWS), dim3(128), 0, stream,
                       indf, x, embed, q, ncs, nea);
    hipLaunchKernelGGL(embed_norm, dim3(CODES), dim3(256), 0, stream, ncs, nea, ne);
}

// Round 3
// 551.525 us; speedup vs baseline: 2.0461x; 1.2443x over previous
//
#include <hip/hip_runtime.h>
#include <cstdint>
#include <cstddef>

#define DECAY 0.8f
#define OMD 0.2f            // 1 - decay
#define EPS_LAP 1e-5f
#define EPS_NORM 1e-6f
#define DELTA 3e-3f         // refinement margin (>4x estimated max bf16 dist error)

constexpr int ROWS  = 8192;   // b*n = 4*2048
constexpr int DIM   = 512;
constexpr int CODES = 8192;

// flat output offsets (floats), in reference return order
constexpr size_t OFF_Q    = 0;
constexpr size_t OFF_IND  = OFF_Q    + (size_t)ROWS * DIM;
constexpr size_t OFF_DIST = OFF_IND  + (size_t)ROWS;
constexpr size_t OFF_NCS  = OFF_DIST + (size_t)ROWS * CODES;
constexpr size_t OFF_NEA  = OFF_NCS  + (size_t)CODES;
constexpr size_t OFF_NE   = OFF_NEA  + (size_t)CODES * DIM;

typedef __bf16 bf16x8_t __attribute__((ext_vector_type(8)));
typedef float  f32x16_t __attribute__((ext_vector_type(16)));

// ---------- helpers ----------

__device__ inline unsigned int ford(float f) {
    unsigned int u = __float_as_uint(f);
    return (u & 0x80000000u) ? ~u : (u | 0x80000000u);
}
__device__ inline float unford(unsigned int u) {
    unsigned int v = (u & 0x80000000u) ? (u & 0x7fffffffu) : ~u;
    return __uint_as_float(v);
}

__device__ inline float block_reduce_sum_256(float v, float* sm) {
    #pragma unroll
    for (int off = 32; off > 0; off >>= 1) v += __shfl_down(v, off, 64);
    __syncthreads();
    if ((threadIdx.x & 63) == 0) sm[threadIdx.x >> 6] = v;
    __syncthreads();
    return sm[0] + sm[1] + sm[2] + sm[3];
}

// ---------- kernel 1: bf16-cast l2norm(x) -> Ah ; bf16(embed) -> Bh ; zero packed ----------

__global__ __launch_bounds__(256) void decompose(
    const float* __restrict__ x, const float* __restrict__ embed,
    unsigned short* __restrict__ Ah, unsigned short* __restrict__ Bh,
    unsigned long long* __restrict__ packed) {
    __shared__ float sm[4];
    const int t = threadIdx.x;
    if ((int)blockIdx.x < ROWS) {
        const int row = blockIdx.x;
        const float2 v = ((const float2*)(x + (size_t)row * DIM))[t];
        const float total = block_reduce_sum_256(v.x * v.x + v.y * v.y, sm);
        const float nx = fmaxf(sqrtf(total), EPS_NORM);
        __bf16 h0 = (__bf16)(v.x / nx), h1 = (__bf16)(v.y / nx);
        ushort2 hh; hh.x = *(unsigned short*)&h0; hh.y = *(unsigned short*)&h1;
        ((ushort2*)(Ah + (size_t)row * DIM))[t] = hh;
    } else {
        const int row = blockIdx.x - ROWS;
        const float2 v = ((const float2*)(embed + (size_t)row * DIM))[t];
        __bf16 h0 = (__bf16)v.x, h1 = (__bf16)v.y;
        ushort2 hh; hh.x = *(unsigned short*)&h0; hh.y = *(unsigned short*)&h1;
        ((ushort2*)(Bh + (size_t)row * DIM))[t] = hh;
        if (t == 0) packed[row] = 0ull;
    }
}

// ---------- kernel 2: bf16 MFMA GEMM dist = xn @ embed^T + fused argmax ----------
// Block tile 128x256, 4 waves in 2x2, each wave 64x128 (2x4 of 32x32x16).
// LDS is FRAGMENT-MAJOR: each (tile, k16-step) frag = 64 lanes x 16B contiguous.

__global__ __launch_bounds__(256, 2) void gemm_bf16(
    const unsigned short* __restrict__ Ah, const unsigned short* __restrict__ Bh,
    float* __restrict__ D,
    unsigned long long* __restrict__ packed,
    unsigned long long* __restrict__ blockkey) {
    // A: 4 row-tiles x 2 k-steps x 64 lanes x 8 shorts = 4096 shorts (8KB)
    // B: 8 col-tiles x 2 k-steps x 64 lanes x 8 shorts = 8192 shorts (16KB)
    __shared__ __align__(16) unsigned short A_s[4 * 2 * 64 * 8];
    __shared__ __align__(16) unsigned short B_s[8 * 2 * 64 * 8];
    __shared__ unsigned long long rowkey[128];

    const int t = threadIdx.x;
    const int bn = blockIdx.x, bm = blockIdx.y;
    const int lane = t & 63, w = t >> 6;
    const int wm = w >> 1, wn = w & 1;
    const int lr = lane & 31, kg = lane >> 5;

    if (t < 128) rowkey[t] = 0ull;

    // ---- staging maps (k-independent) ----
    // loader: c = t&3 (k-octet 0..3 within BK=32), rr = t>>2 (0..63)
    const int c4 = t & 3, rr = t >> 2;
    const int sL = c4 >> 1, kgW = c4 & 1;
    // A: rows rr, rr+64 ; B: rows rr, rr+64, rr+128, rr+192
    const unsigned short* gA0 = Ah + (size_t)(bm * 128 + rr) * DIM + c4 * 8;
    const unsigned short* gA1 = gA0 + (size_t)64 * DIM;
    const unsigned short* gB0 = Bh + (size_t)(bn * 256 + rr) * DIM + c4 * 8;
    const unsigned short* gB1 = gB0 + (size_t)64 * DIM;
    const unsigned short* gB2 = gB0 + (size_t)128 * DIM;
    const unsigned short* gB3 = gB0 + (size_t)192 * DIM;
    // LDS short-index for (block tile bt, step s, lane ln): ((bt*2+s)*64+ln)*8
    const int lnW = (rr & 31) + 32 * kgW;
    const int iA0 = (((rr >> 5) * 2 + sL) * 64 + lnW) * 8;           // rt = rr>>5 (0..1)
    const int iA1 = ((((rr >> 5) + 2) * 2 + sL) * 64 + lnW) * 8;     // rt = 2..3
    const int iB0 = (((rr >> 5) * 2 + sL) * 64 + lnW) * 8;
    const int iB1 = ((((rr >> 5) + 2) * 2 + sL) * 64 + lnW) * 8;
    const int iB2 = ((((rr >> 5) + 4) * 2 + sL) * 64 + lnW) * 8;
    const int iB3 = ((((rr >> 5) + 6) * 2 + sL) * 64 + lnW) * 8;

    f32x16_t acc[2][4];
    #pragma unroll
    for (int i = 0; i < 2; i++)
        #pragma unroll
        for (int j = 0; j < 4; j++)
            #pragma unroll
            for (int r = 0; r < 16; r++) acc[i][j][r] = 0.f;

    float4 pa0 = *(const float4*)gA0;
    float4 pa1 = *(const float4*)gA1;
    float4 pb0 = *(const float4*)gB0;
    float4 pb1 = *(const float4*)gB1;
    float4 pb2 = *(const float4*)gB2;
    float4 pb3 = *(const float4*)gB3;

    // frag read bases (shorts): lane-contiguous
    const int fa0 = (((2 * wm + 0) * 2) * 64 + lane) * 8;
    const int fa1 = (((2 * wm + 1) * 2) * 64 + lane) * 8;
    const int fb  = (((4 * wn) * 2) * 64 + lane) * 8;      // + ctl*2*64*8 + s*64*8

    for (int k0 = 0; k0 < DIM; k0 += 32) {
        __syncthreads();
        *(float4*)&A_s[iA0] = pa0; *(float4*)&A_s[iA1] = pa1;
        *(float4*)&B_s[iB0] = pb0; *(float4*)&B_s[iB1] = pb1;
        *(float4*)&B_s[iB2] = pb2; *(float4*)&B_s[iB3] = pb3;
        __syncthreads();
        if (k0 + 32 < DIM) {
            const int ko = k0 + 32;
            pa0 = *(const float4*)(gA0 + ko); pa1 = *(const float4*)(gA1 + ko);
            pb0 = *(const float4*)(gB0 + ko); pb1 = *(const float4*)(gB1 + ko);
            pb2 = *(const float4*)(gB2 + ko); pb3 = *(const float4*)(gB3 + ko);
        }
        #pragma unroll
        for (int s = 0; s < 2; s++) {
            const int so = s * 64 * 8;
            bf16x8_t a0 = *(const bf16x8_t*)&A_s[fa0 + so];
            bf16x8_t a1 = *(const bf16x8_t*)&A_s[fa1 + so];
            bf16x8_t b0 = *(const bf16x8_t*)&B_s[fb + 0 * 1024 + so];
            bf16x8_t b1 = *(const bf16x8_t*)&B_s[fb + 1 * 1024 + so];
            bf16x8_t b2 = *(const bf16x8_t*)&B_s[fb + 2 * 1024 + so];
            bf16x8_t b3 = *(const bf16x8_t*)&B_s[fb + 3 * 1024 + so];
            acc[0][0] = __builtin_amdgcn_mfma_f32_32x32x16_bf16(a0, b0, acc[0][0], 0, 0, 0);
            acc[0][1] = __builtin_amdgcn_mfma_f32_32x32x16_bf16(a0, b1, acc[0][1], 0, 0, 0);
            acc[0][2] = __builtin_amdgcn_mfma_f32_32x32x16_bf16(a0, b2, acc[0][2], 0, 0, 0);
            acc[0][3] = __builtin_amdgcn_mfma_f32_32x32x16_bf16(a0, b3, acc[0][3], 0, 0, 0);
            acc[1][0] = __builtin_amdgcn_mfma_f32_32x32x16_bf16(a1, b0, acc[1][0], 0, 0, 0);
            acc[1][1] = __builtin_amdgcn_mfma_f32_32x32x16_bf16(a1, b1, acc[1][1], 0, 0, 0);
            acc[1][2] = __builtin_amdgcn_mfma_f32_32x32x16_bf16(a1, b2, acc[1][2], 0, 0, 0);
            acc[1][3] = __builtin_amdgcn_mfma_f32_32x32x16_bf16(a1, b3, acc[1][3], 0, 0, 0);
        }
    }

    // epilogue: store dist + per-row argmax
    // C/D: col = lane&31, row = (reg&3) + 8*(reg>>2) + 4*(lane>>5)
    const int colb = bn * 256 + wn * 128;
    #pragma unroll
    for (int mt = 0; mt < 2; mt++) {
        #pragma unroll
        for (int reg = 0; reg < 16; reg++) {
            const int rloc = wm * 64 + mt * 32 + (reg & 3) + 8 * (reg >> 2) + 4 * kg;
            float* dp = D + (size_t)(bm * 128 + rloc) * CODES + colb + lr;
            unsigned long long key = 0ull;
            #pragma unroll
            for (int ct = 0; ct < 4; ct++) {
                const float v = acc[mt][ct][reg];
                dp[ct * 32] = v;
                unsigned long long k2 =
                    ((unsigned long long)ford(v) << 32) |
                    (unsigned)(CODES - 1 - (colb + ct * 32 + lr));
                if (k2 > key) key = k2;
            }
            #pragma unroll
            for (int m = 1; m <= 16; m <<= 1) {
                unsigned long long o = __shfl_xor(key, m, 64);
                if (o > key) key = o;
            }
            if (lr == 0) atomicMax(&rowkey[rloc], key);
        }
    }
    __syncthreads();
    if (t < 128) {
        const unsigned long long key = rowkey[t];
        const int grow = bm * 128 + t;
        atomicMax(&packed[grow], key);
        blockkey[(size_t)grow * 32 + bn] = key;
    }
}

// ---------- kernel 3: refine argmax exactly (sequential fp32 over candidates) ----------

__global__ __launch_bounds__(64) void refine(
    const unsigned long long* __restrict__ packed,
    const unsigned long long* __restrict__ blockkey,
    const float* __restrict__ D,
    const float* __restrict__ x,
    const float* __restrict__ embed,
    float* __restrict__ indf) {
    const int row = blockIdx.x, t = threadIdx.x;
    __shared__ int cnt;
    __shared__ int cand[64];
    __shared__ float cx[DIM];
    if (t == 0) cnt = 0;
    const unsigned long long pk = packed[row];
    const float m = unford((unsigned int)(pk >> 32));
    const float thr = m - DELTA;
    unsigned long long bk = (t < 32) ? blockkey[(size_t)row * 32 + t] : 0ull;
    const float bv = unford((unsigned int)(bk >> 32));
    unsigned long long bmask = __ballot(t < 32 && bv >= thr);
    __syncthreads();
    while (bmask) {
        const int b = __ffsll((unsigned long long)bmask) - 1;
        bmask &= bmask - 1;
        #pragma unroll
        for (int i = 0; i < 4; i++) {
            const int col = b * 256 + i * 64 + t;
            const float v = D[(size_t)row * CODES + col];
            if (v >= thr) {
                const int p = atomicAdd(&cnt, 1);
                if (p < 64) cand[p] = col;
            }
        }
    }
    __syncthreads();
    const int n = min(cnt, 64);
    int best;
    if (n <= 1) {
        best = CODES - 1 - (int)(pk & 0xffffffffull);
    } else {
        float ss = 0.f;
        for (int k = t; k < DIM; k += 64) { const float xv = x[(size_t)row * DIM + k]; ss += xv * xv; }
        #pragma unroll
        for (int o = 32; o > 0; o >>= 1) ss += __shfl_xor(ss, o, 64);
        const float nx = fmaxf(sqrtf(ss), EPS_NORM);
        for (int k = t; k < DIM; k += 64) cx[k] = x[(size_t)row * DIM + k] / nx;
        __syncthreads();
        unsigned long long bkey = 0ull;
        if (t < n) {
            const int c = cand[t];
            const float* e = embed + (size_t)c * DIM;
            float acc = 0.f;
            for (int k = 0; k < DIM; k++) acc = fmaf(cx[k], e[k], acc);
            bkey = ((unsigned long long)ford(acc) << 32) | (unsigned)(CODES - 1 - c);
        }
        #pragma unroll
        for (int mm = 1; mm <= 32; mm <<= 1) {
            unsigned long long o = __shfl_xor(bkey, mm, 64);
            if (o > bkey) bkey = o;
        }
        best = CODES - 1 - (int)(bkey & 0xffffffffull);
    }
    if (t == 0) indf[row] = (float)best;
}

// ---------- kernel 4: EMA init: ncs = decay*cs, nea = decay*ea ----------

__global__ __launch_bounds__(256) void ema_init(
    const float* __restrict__ cs, const float* __restrict__ ea,
    float* __restrict__ ncs, float* __restrict__ nea) {
    const int gid = blockIdx.x * 256 + threadIdx.x;
    float4 e = ((const float4*)ea)[gid];
    e.x *= DECAY; e.y *= DECAY; e.z *= DECAY; e.w *= DECAY;
    ((float4*)nea)[gid] = e;
    if (gid < CODES / 4) {
        float4 c = ((const float4*)cs)[gid];
        c.x *= DECAY; c.y *= DECAY; c.z *= DECAY; c.w *= DECAY;
        ((float4*)ncs)[gid] = c;
    }
}

// ---------- kernel 5: per-row finalize: quantize gather, bins + embed_sum ----------

__global__ __launch_bounds__(128) void finalize_rows(
    const float* __restrict__ indf, const float* __restrict__ x,
    const float* __restrict__ embed,
    float* __restrict__ q, float* __restrict__ ncs, float* __restrict__ nea) {
    __shared__ float sm[2];
    const int nrow = blockIdx.x, t = threadIdx.x;
    const int c = (int)indf[nrow];
    const int d0 = t * 4;
    const float4 xv = *(const float4*)(x + (size_t)nrow * DIM + d0);
    float ss = xv.x * xv.x + xv.y * xv.y + xv.z * xv.z + xv.w * xv.w;
    #pragma unroll
    for (int o = 32; o > 0; o >>= 1) ss += __shfl_down(ss, o, 64);
    if ((t & 63) == 0) sm[t >> 6] = ss;
    __syncthreads();
    const float nx = fmaxf(sqrtf(sm[0] + sm[1]), EPS_NORM);
    const float4 ev = *(const float4*)(embed + (size_t)c * DIM + d0);
    *(float4*)(q + (size_t)nrow * DIM + d0) = ev;
    float* dst = nea + (size_t)c * DIM + d0;
    atomicAdd(dst + 0, OMD * (xv.x / nx));
    atomicAdd(dst + 1, OMD * (xv.y / nx));
    atomicAdd(dst + 2, OMD * (xv.z / nx));
    atomicAdd(dst + 3, OMD * (xv.w / nx));
    if (t == 0) atomicAdd(&ncs[c], OMD);
}

// ---------- kernel 6: new_embed = l2norm(new_embed_avg / smoothed) ----------

__global__ __launch_bounds__(256) void embed_norm(
    const float* __restrict__ ncs, const float* __restrict__ nea,
    float* __restrict__ ne) {
    __shared__ float sm[4];
    const int c = blockIdx.x;
    const int t = threadIdx.x;
    float local = 0.0f;
    for (int i = t; i < CODES; i += 256) local += ncs[i];
    const float denom = block_reduce_sum_256(local, sm);
    const float s = (ncs[c] + EPS_LAP) / (denom + (float)CODES * EPS_LAP) * denom;
    const float2 v = ((const float2*)(nea + (size_t)c * DIM))[t];
    float2 wv;
    wv.x = v.x / s;
    wv.y = v.y / s;
    const float total = block_reduce_sum_256(wv.x * wv.x + wv.y * wv.y, sm);
    const float norm = fmaxf(sqrtf(total), EPS_NORM);
    float2 o;
    o.x = wv.x / norm;
    o.y = wv.y / norm;
    ((float2*)(ne + (size_t)c * DIM))[t] = o;
}

// ---------- host ----------

extern "C" void kernel_launch(void* const* d_in, const int* in_sizes, int n_in,
                              void* d_out, int out_size, void* d_ws, size_t ws_size,
                              hipStream_t stream) {
    const float* x     = (const float*)d_in[0];
    const float* embed = (const float*)d_in[1];
    const float* cs    = (const float*)d_in[2];
    const float* ea    = (const float*)d_in[3];

    float* out  = (float*)d_out;
    float* q    = out + OFF_Q;
    float* indf = out + OFF_IND;
    float* dist = out + OFF_DIST;
    float* ncs  = out + OFF_NCS;
    float* nea  = out + OFF_NEA;
    float* ne   = out + OFF_NE;

    // scratch aliased into later-written output regions:
    // Ah in new_embed (written last), Bh in quantize (written by finalize),
    // packed+blockkey in new_embed_avg (written by ema_init, after refine).
    unsigned short* Ah = (unsigned short*)ne;
    unsigned short* Bh = (unsigned short*)q;
    unsigned long long* packed   = (unsigned long long*)nea;
    unsigned long long* blockkey = packed + ROWS;   // ROWS*32*8B = 2MB, fits in nea

    hipLaunchKernelGGL(decompose, dim3(ROWS + CODES), dim3(256), 0, stream,
                       x, embed, Ah, Bh, packed);
    hipLaunchKernelGGL(gemm_bf16, dim3(CODES / 256, ROWS / 128), dim3(256), 0, stream,
                       Ah, Bh, dist, packed, blockkey);
    hipLaunchKernelGGL(refine, dim3(ROWS), dim3(64), 0, stream,
                       packed, blockkey, dist, x, embed, indf);
    hipLaunchKernelGGL(ema_init, dim3((CODES * DIM / 4) / 256), dim3(256), 0, stream,
                       cs, ea, ncs, nea);
    hipLaunchKernelGGL(finalize_rows, dim3(ROWS), dim3(128), 0, stream,
                       indf, x, embed, q, ncs, nea);
    hipLaunchKernelGGL(embed_norm, dim3(CODES), dim3(256), 0, stream, ncs, nea, ne);
}